// Round 6
// baseline (893.870 us; speedup 1.0000x reference)
//
#include <hip/hip_runtime.h>
#include <stdint.h>

#define TMASK ((1u << 19) - 1u)
// Embeddings are uniform in [-1e-4, 1e-4]. Scale by 2^13 before fp16
// rounding so every value is a *normal* fp16; power-of-2 scaling is exact,
// added error <= ~3e-8 absolute. Unscale after the trilinear blend.
#define EMB_SCALE     8192.0f
#define EMB_INV_SCALE (1.0f / 8192.0f)

typedef float    vf2 __attribute__((ext_vector_type(2)));
typedef float    vf4 __attribute__((ext_vector_type(4)));
typedef _Float16 vh2 __attribute__((ext_vector_type(2)));
typedef _Float16 vh4 __attribute__((ext_vector_type(4)));

// grid_size = 2/res, fp32 correctly-rounded (compile-time folded), matching
// the reference's fp32 division. Resolutions: floor(16 * b^l), b = 32^(1/15).
static __device__ const float GS_F[16] = {
    2.0f/16.0f, 2.0f/20.0f, 2.0f/25.0f, 2.0f/32.0f,
    2.0f/40.0f, 2.0f/50.0f, 2.0f/64.0f, 2.0f/80.0f,
    2.0f/101.0f, 2.0f/128.0f, 2.0f/161.0f, 2.0f/203.0f,
    2.0f/256.0f, 2.0f/322.0f, 2.0f/406.0f, 2.0f/512.0f};
// res/2 — exact in fp32.
static __device__ const float INVGS_F[16] = {
    8.0f, 10.0f, 12.5f, 16.0f,
    20.0f, 25.0f, 32.0f, 40.0f,
    50.5f, 64.0f, 80.5f, 101.5f,
    128.0f, 161.0f, 203.0f, 256.0f};

// ---- dense-remap geometry for coarse levels 0-3 (res 16,20,25,32) ----
#define N_L0 4913    // 17^3
#define N_L1 9261    // 21^3
#define N_L2 17576   // 26^3
#define N_L3 35937   // 33^3
#define DENSE_OFF1 (N_L0)
#define DENSE_OFF2 (N_L0 + N_L1)
#define DENSE_OFF3 (N_L0 + N_L1 + N_L2)
#define DENSE_TOT  (N_L0 + N_L1 + N_L2 + N_L3)   // 67687 entries = 270.7 KB

#define NBINS 32768   // 32^3 Morton bins for the counting sort

static __device__ const int REMAP_S[4]   = {17, 21, 26, 33};
static __device__ const int REMAP_N[4]   = {N_L0, N_L1, N_L2, N_L3};
static __device__ const int REMAP_OFF[4] = {0, DENSE_OFF1, DENSE_OFF2, DENSE_OFF3};

struct Corner8 { vf2 e[8]; float w[8]; };

__device__ __forceinline__ vf2 load_entry(const vf2* __restrict__ tb, uint32_t h) {
    return tb[h];
}
__device__ __forceinline__ vf2 load_entry(const vh2* __restrict__ tb, uint32_t h) {
    const vh2 v = tb[h];            // one 4 B dword gather
    vf2 r; r.x = (float)v.x; r.y = (float)v.y;
    return r;
}

template <typename T>
__device__ __forceinline__ void gather_level(
    const T* __restrict__ tb, float cx, float cy, float cz,
    float gs, float ivg, Corner8& g)
{
    const float ux = (cx + 1.0f) * ivg;
    const float uy = (cy + 1.0f) * ivg;
    const float uz = (cz + 1.0f) * ivg;
    const float fx = floorf(ux), fy = floorf(uy), fz = floorf(uz);
    const int ix = (int)fx, iy = (int)fy, iz = (int)fz;
    const float wx = (cx - (fx * gs - 1.0f)) * ivg;
    const float wy = (cy - (fy * gs - 1.0f)) * ivg;
    const float wz = (cz - (fz * gs - 1.0f)) * ivg;

    const uint32_t px0 = (uint32_t)ix * 73856093u, px1 = px0 + 73856093u;
    const uint32_t py0 = (uint32_t)iy * 19349663u, py1 = py0 + 19349663u;
    const uint32_t pz0 = (uint32_t)iz * 83492791u, pz1 = pz0 + 83492791u;

    g.e[0] = load_entry(tb, (px0 ^ py0 ^ pz0) & TMASK);
    g.e[1] = load_entry(tb, (px0 ^ py0 ^ pz1) & TMASK);
    g.e[2] = load_entry(tb, (px0 ^ py1 ^ pz0) & TMASK);
    g.e[3] = load_entry(tb, (px0 ^ py1 ^ pz1) & TMASK);
    g.e[4] = load_entry(tb, (px1 ^ py0 ^ pz0) & TMASK);
    g.e[5] = load_entry(tb, (px1 ^ py0 ^ pz1) & TMASK);
    g.e[6] = load_entry(tb, (px1 ^ py1 ^ pz0) & TMASK);
    g.e[7] = load_entry(tb, (px1 ^ py1 ^ pz1) & TMASK);

    const float wxm = 1.0f - wx, wym = 1.0f - wy, wzm = 1.0f - wz;
    const float c00 = wxm * wym, c01 = wxm * wy;
    const float c10 = wx  * wym, c11 = wx  * wy;
    g.w[0] = c00 * wzm; g.w[1] = c00 * wz;
    g.w[2] = c01 * wzm; g.w[3] = c01 * wz;
    g.w[4] = c10 * wzm; g.w[5] = c10 * wz;
    g.w[6] = c11 * wzm; g.w[7] = c11 * wz;
}

__device__ __forceinline__ vf2 blend(const Corner8& g) {
    vf2 r;
    r.x = g.w[0]*g.e[0].x + g.w[1]*g.e[1].x + g.w[2]*g.e[2].x + g.w[3]*g.e[3].x
        + g.w[4]*g.e[4].x + g.w[5]*g.e[5].x + g.w[6]*g.e[6].x + g.w[7]*g.e[7].x;
    r.y = g.w[0]*g.e[0].y + g.w[1]*g.e[1].y + g.w[2]*g.e[2].y + g.w[3]*g.e[3].y
        + g.w[4]*g.e[4].y + g.w[5]*g.e[5].y + g.w[6]*g.e[6].y + g.w[7]*g.e[7].y;
    return r;
}

// ---- counting sort by 15-bit Morton key at 32^3 ----
__device__ __forceinline__ uint32_t spread5(uint32_t v) {
    v &= 31u;
    v = (v | (v << 8)) & 0x0000100Fu;
    v = (v | (v << 4)) & 0x000010C3u;
    v = (v | (v << 2)) & 0x00001249u;
    return v;
}
__device__ __forceinline__ uint32_t morton_key(float cx, float cy, float cz) {
    const int bx = min((int)((cx + 1.0f) * 16.0f), 31);
    const int by = min((int)((cy + 1.0f) * 16.0f), 31);
    const int bz = min((int)((cz + 1.0f) * 16.0f), 31);
    return spread5((uint32_t)bx) | (spread5((uint32_t)by) << 1)
         | (spread5((uint32_t)bz) << 2);
}

__global__ __launch_bounds__(1024) void zero_kernel(uint32_t* h, int n) {
    const int i = blockIdx.x * 1024 + threadIdx.x;
    if (i < n) h[i] = 0u;
}

__global__ __launch_bounds__(256) void hist_kernel(
    const float* __restrict__ x, uint32_t* __restrict__ hist, int B)
{
    const int p = blockIdx.x * 256 + threadIdx.x;
    if (p >= B) return;
    const float cx = fminf(fmaxf(x[3*p+0], -1.0f), 1.0f);
    const float cy = fminf(fmaxf(x[3*p+1], -1.0f), 1.0f);
    const float cz = fminf(fmaxf(x[3*p+2], -1.0f), 1.0f);
    atomicAdd(&hist[morton_key(cx, cy, cz)], 1u);
}

// Exclusive prefix sum over NBINS counters -> running cursors for scatter.
__global__ __launch_bounds__(1024) void scan_kernel(
    const uint32_t* __restrict__ hist, uint32_t* __restrict__ cursor)
{
    __shared__ uint32_t part[1024];
    const int t = threadIdx.x;
    uint32_t loc[32];
    uint32_t s = 0;
#pragma unroll
    for (int i = 0; i < 32; ++i) { loc[i] = s; s += hist[t * 32 + i]; }
    part[t] = s;
    __syncthreads();
    uint32_t acc = 0;
    for (int i = 0; i < t; ++i) acc += part[i];   // broadcast reads: cheap
#pragma unroll
    for (int i = 0; i < 32; ++i) cursor[t * 32 + i] = acc + loc[i];
}

// Scatter points into Morton order: sorted[pos] = {cx,cy,cz, bits(orig idx)}.
__global__ __launch_bounds__(256) void scatter_kernel(
    const float* __restrict__ x, uint32_t* __restrict__ cursor,
    vf4* __restrict__ sorted, int B)
{
    const int p = blockIdx.x * 256 + threadIdx.x;
    if (p >= B) return;
    const float cx = fminf(fmaxf(x[3*p+0], -1.0f), 1.0f);
    const float cy = fminf(fmaxf(x[3*p+1], -1.0f), 1.0f);
    const float cz = fminf(fmaxf(x[3*p+2], -1.0f), 1.0f);
    const uint32_t pos = atomicAdd(&cursor[morton_key(cx, cy, cz)], 1u);
    vf4 v; v.x = cx; v.y = cy; v.z = cz;
    v.w = __uint_as_float((uint32_t)p);
    __builtin_nontemporal_store(v, &sorted[pos]);
}

// fp32 [L][T][2] -> scaled fp16 [L][T][2]. Read 16 B (2 entries), write 8 B.
__global__ __launch_bounds__(256) void convert_kernel(
    const vf4* __restrict__ emb, vh4* __restrict__ tb, int n4)
{
    const int i = blockIdx.x * blockDim.x + threadIdx.x;
    if (i >= n4) return;
    const vf4 v = __builtin_nontemporal_load(emb + i);
    vh4 o;
    o.x = (_Float16)(v.x * EMB_SCALE);
    o.y = (_Float16)(v.y * EMB_SCALE);
    o.z = (_Float16)(v.z * EMB_SCALE);
    o.w = (_Float16)(v.w * EMB_SCALE);
    tb[i] = o;
}

// Build dense fp16 tables for levels 0-3 (exact hash remap, 67687 gathers).
__global__ __launch_bounds__(256) void remap_kernel(
    const vf2* __restrict__ emb, vh2* __restrict__ dense)
{
    const int l = blockIdx.y;
    const int S = REMAP_S[l];
    const int n = REMAP_N[l];
    const int d = blockIdx.x * 256 + threadIdx.x;
    if (d >= n) return;
    const int jz = d % S;
    const int r  = d / S;
    const int jy = r % S;
    const int jx = r / S;
    const uint32_t h = ((uint32_t)jx * 73856093u
                      ^ (uint32_t)jy * 19349663u
                      ^ (uint32_t)jz * 83492791u) & TMASK;
    const vf2 e = emb[((size_t)l << 19) + h];
    vh2 o; o.x = (_Float16)(e.x * EMB_SCALE); o.y = (_Float16)(e.y * EMB_SCALE);
    dense[REMAP_OFF[l] + d] = o;
}

__device__ __forceinline__ vf2 unpack_u32(uint32_t r) {
    const vh2 v = __builtin_bit_cast(vh2, r);
    vf2 o; o.x = (float)v.x; o.y = (float)v.y;
    return o;
}

// One coarse level served from an LDS-resident dense table (DS pipe —
// overlaps with the in-flight global gathers, nearly free).
template <int RES>
__device__ __forceinline__ vf2 coarse_point(
    const uint32_t* __restrict__ tb, float cx, float cy, float cz)
{
    constexpr int S = RES + 1, S2 = S * S;
    constexpr float gs  = 2.0f / (float)RES;
    constexpr float ivg = (float)RES * 0.5f;

    const float ux = (cx + 1.0f) * ivg;
    const float uy = (cy + 1.0f) * ivg;
    const float uz = (cz + 1.0f) * ivg;
    const float fx = floorf(ux), fy = floorf(uy), fz = floorf(uz);
    const int ix = (int)fx, iy = (int)fy, iz = (int)fz;
    const float wx = (cx - (fx * gs - 1.0f)) * ivg;
    const float wy = (cy - (fy * gs - 1.0f)) * ivg;
    const float wz = (cz - (fz * gs - 1.0f)) * ivg;
    const int d0 = (ix * S + iy) * S + iz;

    const vf2 e0 = unpack_u32(tb[d0]);
    const vf2 e1 = unpack_u32(tb[d0 + 1]);
    const vf2 e2 = unpack_u32(tb[d0 + S]);
    const vf2 e3 = unpack_u32(tb[d0 + S + 1]);
    const vf2 e4 = unpack_u32(tb[d0 + S2]);
    const vf2 e5 = unpack_u32(tb[d0 + S2 + 1]);
    const vf2 e6 = unpack_u32(tb[d0 + S2 + S]);
    const vf2 e7 = unpack_u32(tb[d0 + S2 + S + 1]);

    const float wxm = 1.0f - wx, wym = 1.0f - wy, wzm = 1.0f - wz;
    const float c00 = wxm * wym, c01 = wxm * wy;
    const float c10 = wx  * wym, c11 = wx  * wy;
    const float w0 = c00 * wzm, w1 = c00 * wz, w2 = c01 * wzm, w3 = c01 * wz;
    const float w4 = c10 * wzm, w5 = c10 * wz, w6 = c11 * wzm, w7 = c11 * wz;

    vf2 r;
    r.x = w0*e0.x + w1*e1.x + w2*e2.x + w3*e3.x
        + w4*e4.x + w5*e5.x + w6*e6.x + w7*e7.x;
    r.y = w0*e0.y + w1*e1.y + w2*e2.y + w3*e3.y
        + w4*e4.y + w5*e5.y + w6*e6.y + w7*e7.y;
    r.x *= EMB_INV_SCALE; r.y *= EMB_INV_SCALE;
    return r;
}

// Pair kernel over SORTED points: levels {LA, LB} = output float4 slot LA/2,
// written directly to out[origIdx][slot] (no ws round-trip, no transpose).
// Sorted order makes a wave's 64 corner addresses collapse onto the few
// cells the wave's points occupy -> TA merges same-address lanes -> fewer
// unique L2 requests at coarse-fine levels (4-7), plus vL1 temporal hits.
//   CMODE 0: none          (NT=256)
//   CMODE 1: levels 0+1    (NT=1024, 56.7 KB)  -> writes slot 0 too
//   CMODE 2: level 2       (NT=1024, 70.3 KB)  -> writes slot1 lo half
//   CMODE 3: level 3       (NT=1024, 143.7 KB) -> writes slot1 hi half
template <int LA, int LB, int CMODE, int NT>
__global__ __launch_bounds__(NT) void pair_kernel(
    const vf4* __restrict__ sorted,
    const vh2* __restrict__ tbl,
    const uint32_t* __restrict__ dense,
    float* __restrict__ out,     // [B][32] floats = [B][8] float4
    int B, int half)
{
    extern __shared__ uint32_t lds[];
    if constexpr (CMODE == 1) {
        for (int i = threadIdx.x; i < N_L0 + N_L1; i += NT) lds[i] = dense[i];
        __syncthreads();
    } else if constexpr (CMODE == 2) {
        for (int i = threadIdx.x; i < N_L2; i += NT) lds[i] = dense[DENSE_OFF2 + i];
        __syncthreads();
    } else if constexpr (CMODE == 3) {
        for (int i = threadIdx.x; i < N_L3; i += NT) lds[i] = dense[DENSE_OFF3 + i];
        __syncthreads();
    }

    const int p0 = blockIdx.x * NT + threadIdx.x;
    if (p0 >= half) return;
    const int p1 = p0 + half;
    const bool has1 = p1 < B;
    const int p1c = has1 ? p1 : p0;

    const vf4 A = __builtin_nontemporal_load(&sorted[p0]);
    const vf4 Bv = __builtin_nontemporal_load(&sorted[p1c]);
    const float cax = A.x,  cay = A.y,  caz = A.z;
    const float cbx = Bv.x, cby = Bv.y, cbz = Bv.z;
    const uint32_t ia = __float_as_uint(A.w);
    const uint32_t ib = __float_as_uint(Bv.w);

    const vh2* __restrict__ tbA = tbl + ((size_t)LA << 19);
    const vh2* __restrict__ tbB = tbl + ((size_t)LB << 19);
    Corner8 gaA, gbA, gaB, gbB;
    gather_level(tbA, cax, cay, caz, GS_F[LA], INVGS_F[LA], gaA);
    gather_level(tbA, cbx, cby, cbz, GS_F[LA], INVGS_F[LA], gbA);
    gather_level(tbB, cax, cay, caz, GS_F[LB], INVGS_F[LB], gaB);
    gather_level(tbB, cbx, cby, cbz, GS_F[LB], INVGS_F[LB], gbB);

    // Coarse LDS work while global gathers are in flight.
    vf2 c0a, c0b, c1a, c1b;
    if constexpr (CMODE == 1) {
        c0a = coarse_point<16>(lds, cax, cay, caz);
        c0b = coarse_point<16>(lds, cbx, cby, cbz);
        c1a = coarse_point<20>(lds + N_L0, cax, cay, caz);
        c1b = coarse_point<20>(lds + N_L0, cbx, cby, cbz);
    } else if constexpr (CMODE == 2) {
        c0a = coarse_point<25>(lds, cax, cay, caz);
        c0b = coarse_point<25>(lds, cbx, cby, cbz);
    } else if constexpr (CMODE == 3) {
        c0a = coarse_point<32>(lds, cax, cay, caz);
        c0b = coarse_point<32>(lds, cbx, cby, cbz);
    }

    vf2 rA = blend(gaA), rB = blend(gaB);
    vf2 sA = blend(gbA), sB = blend(gbB);
    constexpr int slot = LA / 2;
    {
        vf4 v; v.x = rA.x * EMB_INV_SCALE; v.y = rA.y * EMB_INV_SCALE;
        v.z = rB.x * EMB_INV_SCALE; v.w = rB.y * EMB_INV_SCALE;
        __builtin_nontemporal_store(v, (vf4*)(out + (size_t)ia * 32 + slot * 4));
    }
    if (has1) {
        vf4 v; v.x = sA.x * EMB_INV_SCALE; v.y = sA.y * EMB_INV_SCALE;
        v.z = sB.x * EMB_INV_SCALE; v.w = sB.y * EMB_INV_SCALE;
        __builtin_nontemporal_store(v, (vf4*)(out + (size_t)ib * 32 + slot * 4));
    }

    if constexpr (CMODE == 1) {
        vf4 v; v.x = c0a.x; v.y = c0a.y; v.z = c1a.x; v.w = c1a.y;
        __builtin_nontemporal_store(v, (vf4*)(out + (size_t)ia * 32));
        if (has1) {
            vf4 w; w.x = c0b.x; w.y = c0b.y; w.z = c1b.x; w.w = c1b.y;
            __builtin_nontemporal_store(w, (vf4*)(out + (size_t)ib * 32));
        }
    } else if constexpr (CMODE == 2) {
        __builtin_nontemporal_store(c0a, (vf2*)(out + (size_t)ia * 32 + 4));
        if (has1)
            __builtin_nontemporal_store(c0b, (vf2*)(out + (size_t)ib * 32 + 4));
    } else if constexpr (CMODE == 3) {
        __builtin_nontemporal_store(c0a, (vf2*)(out + (size_t)ia * 32 + 6));
        if (has1)
            __builtin_nontemporal_store(c0b, (vf2*)(out + (size_t)ib * 32 + 6));
    }
}

// Fallback (workspace too small): fp32 monolith, needs no workspace.
__global__ __launch_bounds__(256) void monolith_kernel(
    const float* __restrict__ x,
    const vf2* __restrict__ tbl,
    vf4* __restrict__ out,
    int B, int half)
{
    const int t = threadIdx.x;
    const int base = blockIdx.x * 256;
    const int p0r = base + t;
    const int p0 = p0r < half ? p0r : half - 1;
    const int p1r = p0 + half;
    const int p1 = p1r < B ? p1r : B - 1;

    const float cax = fminf(fmaxf(__builtin_nontemporal_load(x + 3*p0 + 0), -1.0f), 1.0f);
    const float cay = fminf(fmaxf(__builtin_nontemporal_load(x + 3*p0 + 1), -1.0f), 1.0f);
    const float caz = fminf(fmaxf(__builtin_nontemporal_load(x + 3*p0 + 2), -1.0f), 1.0f);
    const float cbx = fminf(fmaxf(__builtin_nontemporal_load(x + 3*p1 + 0), -1.0f), 1.0f);
    const float cby = fminf(fmaxf(__builtin_nontemporal_load(x + 3*p1 + 1), -1.0f), 1.0f);
    const float cbz = fminf(fmaxf(__builtin_nontemporal_load(x + 3*p1 + 2), -1.0f), 1.0f);

    vf2 oa[16], ob[16];
#pragma unroll
    for (int l = 0; l < 16; ++l) {
        const vf2* __restrict__ tb = tbl + ((size_t)l << 19);
        Corner8 ga, gb;
        gather_level(tb, cax, cay, caz, GS_F[l], INVGS_F[l], ga);
        gather_level(tb, cbx, cby, cbz, GS_F[l], INVGS_F[l], gb);
        oa[l] = blend(ga); ob[l] = blend(gb);
    }

    __shared__ vf2 tile[16][257];
#pragma unroll
    for (int l = 0; l < 16; ++l) tile[l][t] = oa[l];
    __syncthreads();
#pragma unroll
    for (int k = 0; k < 8; ++k) {
        const int flat = k * 256 + t;
        const int p = flat >> 3;
        const int j = flat & 7;
        if (base + p < half) {
            const vf2 a = tile[2*j][p];
            const vf2 c = tile[2*j+1][p];
            vf4 v; v.x = a.x; v.y = a.y; v.z = c.x; v.w = c.y;
            __builtin_nontemporal_store(v, &out[(long)(base + p) * 8 + j]);
        }
    }
    __syncthreads();
#pragma unroll
    for (int l = 0; l < 16; ++l) tile[l][t] = ob[l];
    __syncthreads();
#pragma unroll
    for (int k = 0; k < 8; ++k) {
        const int flat = k * 256 + t;
        const int p = flat >> 3;
        const int j = flat & 7;
        const long pt = (long)base + half + p;
        if (pt < B) {
            const vf2 a = tile[2*j][p];
            const vf2 c = tile[2*j+1][p];
            vf4 v; v.x = a.x; v.y = a.y; v.z = c.x; v.w = c.y;
            __builtin_nontemporal_store(v, &out[pt * 8 + j]);
        }
    }
}

extern "C" void kernel_launch(void* const* d_in, const int* in_sizes, int n_in,
                              void* d_out, int out_size, void* d_ws, size_t ws_size,
                              hipStream_t stream) {
    const float* x   = (const float*)d_in[0];
    const float* emb = (const float*)d_in[1];
    const int B = in_sizes[0] / 3;

    const int half = (B + 1) / 2;

    // Workspace layout (all in d_ws):
    const size_t tbl_bytes    = (size_t)16 * 524288 * sizeof(vh2);  // 32 MB
    const size_t sorted_off   = tbl_bytes;
    const size_t sorted_bytes = (size_t)B * sizeof(vf4);            // 16 MB @1M
    const size_t hist_off     = sorted_off + sorted_bytes;
    const size_t hist_bytes   = (size_t)NBINS * 4;
    const size_t cursor_off   = hist_off + hist_bytes;
    const size_t dense_off    = cursor_off + hist_bytes;
    const size_t need         = dense_off + (size_t)DENSE_TOT * sizeof(vh2);

    if (ws_size >= need) {
        vh2* tb          = (vh2*)d_ws;
        vf4* sorted      = (vf4*)((char*)d_ws + sorted_off);
        uint32_t* hist   = (uint32_t*)((char*)d_ws + hist_off);
        uint32_t* cursor = (uint32_t*)((char*)d_ws + cursor_off);
        vh2* dense       = (vh2*)((char*)d_ws + dense_off);
        const uint32_t* dn = (const uint32_t*)dense;

        static int attr_done = 0;
        if (!attr_done) {
            (void)hipFuncSetAttribute(
                reinterpret_cast<const void*>(&pair_kernel<4, 5, 1, 1024>),
                hipFuncAttributeMaxDynamicSharedMemorySize, (N_L0 + N_L1) * 4);
            (void)hipFuncSetAttribute(
                reinterpret_cast<const void*>(&pair_kernel<6, 7, 2, 1024>),
                hipFuncAttributeMaxDynamicSharedMemorySize, N_L2 * 4);
            (void)hipFuncSetAttribute(
                reinterpret_cast<const void*>(&pair_kernel<8, 9, 3, 1024>),
                hipFuncAttributeMaxDynamicSharedMemorySize, N_L3 * 4);
            attr_done = 1;
        }

        const int gB = (B + 255) / 256;

        // 1) fp16 tables + dense coarse tables
        const int n4 = 16 * 524288 * 2 / 4;
        convert_kernel<<<(n4 + 255) / 256, 256, 0, stream>>>(
            (const vf4*)emb, (vh4*)tb, n4);
        remap_kernel<<<dim3((N_L3 + 255) / 256, 4), 256, 0, stream>>>(
            (const vf2*)emb, dense);

        // 2) Morton counting-sort of the points
        zero_kernel<<<(NBINS + 1023) / 1024, 1024, 0, stream>>>(hist, NBINS);
        hist_kernel<<<gB, 256, 0, stream>>>(x, hist, B);
        scan_kernel<<<1, 1024, 0, stream>>>(hist, cursor);
        scatter_kernel<<<gB, 256, 0, stream>>>(x, cursor, sorted, B);

        // 3) pair kernels (sorted order), writing output slots directly
        const int g1024 = (half + 1023) / 1024;
        const int g256  = (half + 255) / 256;
        pair_kernel<4, 5, 1, 1024><<<g1024, 1024, (N_L0 + N_L1) * 4, stream>>>(
            sorted, tb, dn, (float*)d_out, B, half);
        pair_kernel<6, 7, 2, 1024><<<g1024, 1024, N_L2 * 4, stream>>>(
            sorted, tb, dn, (float*)d_out, B, half);
        pair_kernel<8, 9, 3, 1024><<<g1024, 1024, N_L3 * 4, stream>>>(
            sorted, tb, dn, (float*)d_out, B, half);
        pair_kernel<10, 11, 0, 256><<<g256, 256, 0, stream>>>(
            sorted, tb, dn, (float*)d_out, B, half);
        pair_kernel<12, 13, 0, 256><<<g256, 256, 0, stream>>>(
            sorted, tb, dn, (float*)d_out, B, half);
        pair_kernel<14, 15, 0, 256><<<g256, 256, 0, stream>>>(
            sorted, tb, dn, (float*)d_out, B, half);
    } else {
        const int grid = (half + 255) / 256;
        monolith_kernel<<<grid, 256, 0, stream>>>(
            x, (const vf2*)emb, (vf4*)d_out, B, half);
    }
}